// Round 19
// baseline (6322.663 us; speedup 1.0000x reference)
//
#include <hip/hip_runtime.h>

#define U_CNT 16384
#define I_CNT 8192
#define DIM 64
#define BAND 16                   // rows per band
#define CHUNK 256                 // cols owned by one block (fixed)
#define NSTEP 32                  // bands per group sweep
#define LDS_STRIDE 260            // floats; writes 2-way (free), reads clean
#define NEG_LOG2E (-1.4426950408889634f)

typedef __bf16 bf16x8 __attribute__((ext_vector_type(8)));
typedef float f32x4 __attribute__((ext_vector_type(4)));
typedef unsigned short ushort4v __attribute__((ext_vector_type(4)));

__device__ __forceinline__ unsigned short f32_to_bf16_rtn(float f) {
    unsigned int b = __float_as_uint(f);
    b += 0x7fffu + ((b >> 16) & 1u);
    return (unsigned short)(b >> 16);
}

// Prep: blocks [0, 2048) convert Q1 -> bf16 (and clear the 1024 band-flags);
// blocks [2048, ...) scan seg_ids for segment boundaries (every user has
// >=1 item -> every bounds[u] written exactly once; bounds[U_CNT] = nnz).
// Kernel-boundary flush makes all of this visible to the fused kernel.
__global__ __launch_bounds__(256) void prep_kernel(
    const float* __restrict__ Q1, unsigned short* __restrict__ Q1bf,
    const int* __restrict__ segs, int nnz, int* __restrict__ bounds,
    int* __restrict__ flags)
{
    if (blockIdx.x < 2048) {
        int i = blockIdx.x * 256 + threadIdx.x;   // covers I_CNT*DIM = 524288
        Q1bf[i] = f32_to_bf16_rtn(Q1[i]);
        if (i < 1024) flags[i] = 0;               // re-armed every call (replay-safe)
    } else {
        int i = (blockIdx.x - 2048) * 256 + threadIdx.x;
        if (i >= nnz) return;
        if (i == 0) bounds[segs[0]] = 0;
        else if (segs[i] != segs[i - 1]) bounds[segs[i]] = i;
        if (i == nnz - 1) bounds[U_CNT] = nnz;
    }
}

// Produce 4 users of band bidx (users bidx*16 + wave*4 .. +3) with the R12
// quarter-wave gather. Pbf rows written NONTEMPORAL (bypass L2 -> L3) so
// consumers on other XCDs see them; caller drains vmcnt via its barrier
// before publishing the flag.
__device__ __forceinline__ void produce_band(
    int bidx, int wave, int lane,
    const float* __restrict__ Q2, const float* __restrict__ P,
    const int* __restrict__ items, const int* __restrict__ bounds,
    unsigned short* __restrict__ Pbf)
{
    const int qg = lane >> 4, ql = lane & 15;
#pragma unroll
    for (int t = 0; t < 4; ++t) {
        const int u = bidx * BAND + wave * 4 + t;
        const int start = bounds[u], end = bounds[u + 1];
        const int cnt = end - start;              // guaranteed >= 1
        f32x4 acc0 = {0.f, 0.f, 0.f, 0.f}, acc1 = {0.f, 0.f, 0.f, 0.f};
        int j = start + qg;
        for (; j + 4 < end; j += 8) {
            f32x4 v0 = *reinterpret_cast<const f32x4*>(&Q2[items[j] * DIM + ql * 4]);
            f32x4 v1 = *reinterpret_cast<const f32x4*>(&Q2[items[j + 4] * DIM + ql * 4]);
            acc0 += v0;
            acc1 += v1;
        }
        if (j < end)
            acc0 += *reinterpret_cast<const f32x4*>(&Q2[items[j] * DIM + ql * 4]);
        f32x4 acc = acc0 + acc1;
#pragma unroll
        for (int e = 0; e < 4; ++e) {
            acc[e] += __shfl_xor(acc[e], 16, 64);
            acc[e] += __shfl_xor(acc[e], 32, 64);
        }
        if (qg == 0) {
            f32x4 pv = *reinterpret_cast<const f32x4*>(&P[u * DIM + ql * 4]);
            float rs = rsqrtf((float)cnt);
            ushort4v o;
#pragma unroll
            for (int e = 0; e < 4; ++e)
                o[e] = f32_to_bf16_rtn(acc[e] * rs + pv[e]);
            __builtin_nontemporal_store(o,
                reinterpret_cast<ushort4v*>(&Pbf[u * DIM + ql * 4]));
        }
    }
}

// Fused producer-consumer coordinated-window GEMM + sigmoid.
// Geometry/stores identical to the 114.8us champion: 1024 blocks (32 groups
// x 32 members), fixed 256-col chunk, dbuf LDS, 1 barrier/step, 1 KB nt
// store per row, 16 MB step-window. NEW: block (g,m) also PRODUCES P_full
// band g+m*32 (members 0,1 in a pre-phase; member m>=2 during its step m-2),
// publishing flags[band] (agent release) after the step barrier whose
// implicit vmcnt(0) drained the nt Pbf stores. Consumers acquire-spin on
// flags[band] before each step's A-frag loads. Dependencies point strictly
// backward in step index (no cycles); __launch_bounds__(256,4) + 33KB LDS
// pin 4 blocks/CU = all 1024 co-resident; bounded-spin self-production
// fallback (idempotent, identical bytes) makes deadlock impossible.
// This hides pfull's ~8us of L2-bound gather under HBM-store-bound steps.
__global__ __launch_bounds__(256, 4) void fused_kernel(
    const float* __restrict__ Q2, const float* __restrict__ P,
    const int* __restrict__ items, const int* __restrict__ bounds,
    unsigned short* __restrict__ Pbf, const unsigned short* __restrict__ Bbf,
    const float* __restrict__ bu, const float* __restrict__ bi,
    int* __restrict__ flags, float* __restrict__ out)
{
    const int lane = threadIdx.x & 63;
    const int wid  = threadIdx.x >> 6;      // 0..3: 64-col sub-band within chunk
    const int r = lane & 15, g = lane >> 4;
    const int member = blockIdx.x & 31;     // fixed col chunk
    const int group  = blockIdx.x >> 5;     // 0..31
    const int colbase = member * CHUNK;
    const int col0 = colbase + wid * 64;
    const int myband = group + member * 32; // band this block produces

    __shared__ float lds[2][BAND][LDS_STRIDE];   // 33.3 KB -> 4 blocks/CU

    // B fragments + bi: loaded ONCE, register-resident for the whole kernel.
    bf16x8 b[4][2];
    float bi_f[4];
#pragma unroll
    for (int nf = 0; nf < 4; ++nf) {
        bi_f[nf] = bi[col0 + nf * 16 + r] + 0.05f;   // fold the +0.05 here
#pragma unroll
        for (int ks = 0; ks < 2; ++ks)
            b[nf][ks] = *reinterpret_cast<const bf16x8*>(
                &Bbf[(col0 + nf * 16 + r) * DIM + ks * 32 + g * 8]);
    }

    // Pre-phase: members 0,1 produce their bands (needed at steps 0,1).
    if (member < 2)
        produce_band(myband, wid, lane, Q2, P, items, bounds, Pbf);
    __syncthreads();   // implicit vmcnt(0) drains the nt Pbf stores
    if (member < 2 && threadIdx.x == 0)
        __hip_atomic_store(&flags[myband], 1, __ATOMIC_RELEASE,
                           __HIP_MEMORY_SCOPE_AGENT);

    for (int s = 0; s < NSTEP; ++s) {
        const int bidx = group + s * 32;
        const int p = s & 1;

        // Steady-state production: block (g,m) produces its band at step m-2.
        if (member == s + 2)
            produce_band(myband, wid, lane, Q2, P, items, bounds, Pbf);

        // Wait for this step's band (acquire orders the A-frag loads below).
        {
            int k = 0;
            while (__hip_atomic_load(&flags[bidx], __ATOMIC_ACQUIRE,
                                     __HIP_MEMORY_SCOPE_AGENT) == 0) {
                __builtin_amdgcn_s_sleep(8);
                if (++k > (1 << 17)) {        // never in practice: self-produce
                    for (int w = 0; w < 4; ++w)
                        produce_band(bidx, w, lane, Q2, P, items, bounds, Pbf);
                    __asm__ volatile("s_waitcnt vmcnt(0)" ::: "memory");
                    break;
                }
            }
        }

        const int row0 = bidx * BAND;

        // A fragment for this band (rows row0..row0+15), both K-steps.
        bf16x8 a[2];
#pragma unroll
        for (int ks = 0; ks < 2; ++ks)
            a[ks] = *reinterpret_cast<const bf16x8*>(
                &Pbf[(row0 + r) * DIM + ks * 32 + g * 8]);

        float bu_g[4];
#pragma unroll
        for (int j = 0; j < 4; ++j) bu_g[j] = bu[row0 + g * 4 + j];

        f32x4 acc[4] = {};
#pragma unroll
        for (int ks = 0; ks < 2; ++ks)
#pragma unroll
            for (int nf = 0; nf < 4; ++nf)
                acc[nf] = __builtin_amdgcn_mfma_f32_16x16x32_bf16(
                    a[ks], b[nf][ks], acc[nf], 0, 0, 0);

        // Sigmoid in acc layout, write into buffer p of the tile.
#pragma unroll
        for (int nf = 0; nf < 4; ++nf)
#pragma unroll
            for (int j = 0; j < 4; ++j) {
                float x = (acc[nf][j] + bu_g[j] + bi_f[nf]) * NEG_LOG2E;
                float e = __builtin_amdgcn_exp2f(x);
                float v = 5.f * __builtin_amdgcn_rcpf(1.f + e);
                lds[p][g * 4 + j][wid * 64 + nf * 16 + r] = v;
            }

        __syncthreads();   // drains this block's nt Pbf production stores too

        // Publish the band produced this step (data drained by the barrier).
        if (member == s + 2 && threadIdx.x == 0)
            __hip_atomic_store(&flags[myband], 1, __ATOMIC_RELEASE,
                               __HIP_MEMORY_SCOPE_AGENT);

        // Store phase: wave wid owns rows wid*4..+3. ONE instruction per
        // row: 1 KB fully contiguous, nontemporal. No trailing barrier.
#pragma unroll
        for (int i = 0; i < 4; ++i) {
            const int row = wid * 4 + i;
            f32x4 v = *reinterpret_cast<const f32x4*>(&lds[p][row][lane * 4]);
            __builtin_nontemporal_store(v, reinterpret_cast<f32x4*>(
                &out[(size_t)(row0 + row) * I_CNT + colbase + lane * 4]));
        }
    }
}

extern "C" void kernel_launch(void* const* d_in, const int* in_sizes, int n_in,
                              void* d_out, int out_size, void* d_ws, size_t ws_size,
                              hipStream_t stream)
{
    const float* Q1 = (const float*)d_in[0];
    const float* Q2 = (const float*)d_in[1];
    const float* P  = (const float*)d_in[2];
    const float* bu = (const float*)d_in[3];
    const float* bi = (const float*)d_in[4];
    const int* items = (const int*)d_in[5];
    const int* segs  = (const int*)d_in[6];
    const int nnz = in_sizes[5];

    unsigned short* Pbf  = (unsigned short*)d_ws;            // 2 MB
    unsigned short* Q1bf = Pbf + U_CNT * DIM;                // 1 MB
    int* bounds = (int*)(Q1bf + I_CNT * DIM);                // 64 KB + 4 B
    int* flags  = bounds + (U_CNT + 1);                      // 4 KB

    int boundsBlocks = (nnz + 255) / 256;
    prep_kernel<<<2048 + boundsBlocks, 256, 0, stream>>>(
        Q1, Q1bf, segs, nnz, bounds, flags);
    // 32 groups x 32 members = 1024 blocks, all co-resident at 4 blocks/CU.
    fused_kernel<<<32 * 32, 256, 0, stream>>>(
        Q2, P, items, bounds, Pbf, Q1bf, bu, bi, flags, (float*)d_out);
}

// Round 20
// 115.281 us; speedup vs baseline: 54.8456x; 54.8456x over previous
//
#include <hip/hip_runtime.h>

#define U_CNT 16384
#define I_CNT 8192
#define DIM 64
#define BAND 16                   // rows per band (per block per step)
#define CHUNK 256                 // cols owned by one block (fixed)
#define NSTEP 32                  // bands per group sweep
#define LDS_STRIDE 260            // floats; writes 2-way (free), reads clean
#define NEG_LOG2E (-1.4426950408889634f)

typedef __bf16 bf16x8 __attribute__((ext_vector_type(8)));
typedef float f32x4 __attribute__((ext_vector_type(4)));
typedef unsigned short ushort4v __attribute__((ext_vector_type(4)));

__device__ __forceinline__ unsigned short f32_to_bf16_rtn(float f) {
    unsigned int b = __float_as_uint(f);
    b += 0x7fffu + ((b >> 16) & 1u);
    return (unsigned short)(b >> 16);
}

// Prep: blocks [0, 2048) convert Q1 -> bf16; blocks [2048, ...) scan seg_ids
// for segment boundaries (every user has >=1 item -> every bounds[u] written
// exactly once; bounds[U_CNT] = nnz).
__global__ __launch_bounds__(256) void prep_kernel(
    const float* __restrict__ Q1, unsigned short* __restrict__ Q1bf,
    const int* __restrict__ segs, int nnz, int* __restrict__ bounds)
{
    if (blockIdx.x < 2048) {
        int i = blockIdx.x * 256 + threadIdx.x;   // covers I_CNT*DIM = 524288
        Q1bf[i] = f32_to_bf16_rtn(Q1[i]);
    } else {
        int i = (blockIdx.x - 2048) * 256 + threadIdx.x;
        if (i >= nnz) return;
        if (i == 0) bounds[segs[0]] = 0;
        else if (segs[i] != segs[i - 1]) bounds[segs[i]] = i;
        if (i == nnz - 1) bounds[U_CNT] = nnz;
    }
}

// One wave per user, quarter-wave per item (R12 vectorized gather):
// lane l loads a 16B f32x4 of row items[j + (l>>4)], dims 4*(l&15)..+3;
// dual accumulators; 8-shuffle cross-quarter reduce; lanes 0-15 finalize
// with an 8B ushort4 bf16 store.
__global__ __launch_bounds__(256) void pfull_kernel(
    const float* __restrict__ Q2, const float* __restrict__ P,
    const int* __restrict__ items, const int* __restrict__ bounds,
    unsigned short* __restrict__ Pbf)
{
    const int u = (blockIdx.x * 256 + threadIdx.x) >> 6;
    const int lane = threadIdx.x & 63;
    if (u >= U_CNT) return;
    const int qg = lane >> 4;       // quarter-group: which item in a 4-pack
    const int ql = lane & 15;       // dim slot: 16 lanes x f32x4 = 64 dims

    const int start = bounds[u];
    const int end   = bounds[u + 1];
    const int cnt   = end - start;  // guaranteed >= 1

    f32x4 acc0 = {0.f, 0.f, 0.f, 0.f}, acc1 = {0.f, 0.f, 0.f, 0.f};
    int j = start + qg;
    for (; j + 4 < end; j += 8) {
        int i0 = items[j], i1 = items[j + 4];
        f32x4 v0 = *reinterpret_cast<const f32x4*>(&Q2[i0 * DIM + ql * 4]);
        f32x4 v1 = *reinterpret_cast<const f32x4*>(&Q2[i1 * DIM + ql * 4]);
        acc0 += v0;
        acc1 += v1;
    }
    if (j < end)
        acc0 += *reinterpret_cast<const f32x4*>(&Q2[items[j] * DIM + ql * 4]);
    f32x4 acc = acc0 + acc1;

    // Reduce across the 4 quarter-groups (lanes l, l+16, l+32, l+48).
#pragma unroll
    for (int e = 0; e < 4; ++e) {
        acc[e] += __shfl_xor(acc[e], 16, 64);
        acc[e] += __shfl_xor(acc[e], 32, 64);
    }

    if (qg == 0) {
        f32x4 pv = *reinterpret_cast<const f32x4*>(&P[u * DIM + ql * 4]);
        float rs = rsqrtf((float)cnt);
        ushort4v o;
#pragma unroll
        for (int e = 0; e < 4; ++e)
            o[e] = f32_to_bf16_rtn(acc[e] * rs + pv[e]);
        *reinterpret_cast<ushort4v*>(&Pbf[u * DIM + ql * 4]) = o;
    }
}

// Coordinated-window GEMM + sigmoid — the R14 champion (114.8us).
// Grid = 1024 blocks (32 groups x 32 members). Block b: member = b&31 owns
// fixed cols [member*256, +256); group = b>>5. Step s: band (group + s*32).
// At step s the whole GPU writes rows [s*512, +512) = a contiguous 16 MB
// window sweeping linearly (fill-kernel shape). B fragments + bi register-
// resident; per step only the 2-instr A fragment + bu reload. Epilogue:
// sigmoid in acc layout -> block-wide LDS tile [16][260] (one barrier before
// store phase, one after) -> wave wid owns rows wid*4..+3, ONE f32x4 nt
// store instruction per row = 1 KB fully contiguous (granule optimum; 2 KB
// regresses, cached stores regress, scattered 256B regresses).
__global__ __launch_bounds__(256) void gemm_sig_kernel(
    const unsigned short* __restrict__ Abf, const unsigned short* __restrict__ Bbf,
    const float* __restrict__ bu, const float* __restrict__ bi,
    float* __restrict__ out)
{
    const int lane = threadIdx.x & 63;
    const int wid  = threadIdx.x >> 6;      // 0..3: 64-col sub-band within chunk
    const int r = lane & 15, g = lane >> 4;
    const int member = blockIdx.x & 31;     // fixed col chunk
    const int group  = blockIdx.x >> 5;     // 0..31
    const int colbase = member * CHUNK;
    const int col0 = colbase + wid * 64;

    __shared__ float lds[BAND][LDS_STRIDE];   // block-wide tile

    // B fragments + bi: loaded ONCE, register-resident for the whole kernel.
    bf16x8 b[4][2];
    float bi_f[4];
#pragma unroll
    for (int nf = 0; nf < 4; ++nf) {
        bi_f[nf] = bi[col0 + nf * 16 + r] + 0.05f;   // fold the +0.05 here
#pragma unroll
        for (int ks = 0; ks < 2; ++ks)
            b[nf][ks] = *reinterpret_cast<const bf16x8*>(
                &Bbf[(col0 + nf * 16 + r) * DIM + ks * 32 + g * 8]);
    }

    for (int s = 0; s < NSTEP; ++s) {
        const int band = (group + s * 32) * BAND;

        // A fragment for this band (rows band..band+15), both K-steps.
        bf16x8 a[2];
#pragma unroll
        for (int ks = 0; ks < 2; ++ks)
            a[ks] = *reinterpret_cast<const bf16x8*>(
                &Abf[(band + r) * DIM + ks * 32 + g * 8]);

        float bu_g[4];
#pragma unroll
        for (int j = 0; j < 4; ++j) bu_g[j] = bu[band + g * 4 + j];

        f32x4 acc[4] = {};
#pragma unroll
        for (int ks = 0; ks < 2; ++ks)
#pragma unroll
            for (int nf = 0; nf < 4; ++nf)
                acc[nf] = __builtin_amdgcn_mfma_f32_16x16x32_bf16(
                    a[ks], b[nf][ks], acc[nf], 0, 0, 0);

        // Sigmoid in acc layout (row = g*4+j, col = wid*64 + nf*16 + r),
        // write into the block-wide tile.
#pragma unroll
        for (int nf = 0; nf < 4; ++nf)
#pragma unroll
            for (int j = 0; j < 4; ++j) {
                float x = (acc[nf][j] + bu_g[j] + bi_f[nf]) * NEG_LOG2E;
                float e = __builtin_amdgcn_exp2f(x);
                float v = 5.f * __builtin_amdgcn_rcpf(1.f + e);
                lds[g * 4 + j][wid * 64 + nf * 16 + r] = v;
            }

        __syncthreads();

        // Store phase: wave wid owns rows wid*4..wid*4+3. ONE instruction
        // per row: 64 lanes x f32x4 = 1 KB fully contiguous, nontemporal.
#pragma unroll
        for (int i = 0; i < 4; ++i) {
            const int row = wid * 4 + i;
            f32x4 v = *reinterpret_cast<const f32x4*>(&lds[row][lane * 4]);
            __builtin_nontemporal_store(v, reinterpret_cast<f32x4*>(
                &out[(size_t)(band + row) * I_CNT + colbase + lane * 4]));
        }

        __syncthreads();   // protect tile reuse by next step
    }
}

extern "C" void kernel_launch(void* const* d_in, const int* in_sizes, int n_in,
                              void* d_out, int out_size, void* d_ws, size_t ws_size,
                              hipStream_t stream)
{
    const float* Q1 = (const float*)d_in[0];
    const float* Q2 = (const float*)d_in[1];
    const float* P  = (const float*)d_in[2];
    const float* bu = (const float*)d_in[3];
    const float* bi = (const float*)d_in[4];
    const int* items = (const int*)d_in[5];
    const int* segs  = (const int*)d_in[6];
    const int nnz = in_sizes[5];

    unsigned short* Pbf  = (unsigned short*)d_ws;            // 2 MB
    unsigned short* Q1bf = Pbf + U_CNT * DIM;                // 1 MB
    int* bounds = (int*)(Q1bf + I_CNT * DIM);                // 64 KB + 4 B

    int boundsBlocks = (nnz + 255) / 256;
    prep_kernel<<<2048 + boundsBlocks, 256, 0, stream>>>(Q1, Q1bf, segs, nnz, bounds);
    pfull_kernel<<<U_CNT / 4, 256, 0, stream>>>(Q2, P, items, bounds, Pbf);
    // 32 groups x 32 members = 1024 blocks; each block sweeps NSTEP=32 bands.
    gemm_sig_kernel<<<32 * 32, 256, 0, stream>>>(Pbf, Q1bf, bu, bi, (float*)d_out);
}